// Round 5
// baseline (326.198 us; speedup 1.0000x reference)
//
#include <hip/hip_runtime.h>
#include <hip/hip_bf16.h>

#define B_ 32
#define N_ 2048
#define D_ 512
#define KC_ 64
#define KG_ 80
#define M_ (B_*N_)   // 65536

typedef __attribute__((ext_vector_type(8))) short short8;
typedef __attribute__((ext_vector_type(4))) float f32x4;

__device__ __forceinline__ unsigned short bf_rn(float f){
  unsigned int u = __float_as_uint(f);
  unsigned int r = u + 0x7FFFu + ((u >> 16) & 1u);
  return (unsigned short)(r >> 16);
}
__device__ __forceinline__ float bf_up(unsigned short h){
  return __uint_as_float(((unsigned int)h) << 16);
}
__device__ __forceinline__ void cvt8(const float* v, short8& hi, short8& lo){
#pragma unroll
  for (int i=0;i<8;i++){
    unsigned short h = bf_rn(v[i]);
    float rem = v[i] - bf_up(h);
    hi[i] = (short)h;
    lo[i] = (short)bf_rn(rem);
  }
}

// ---------------- K0: clusters -> fragment-ordered bf16 hi/lo --------------
// chunk c (32 k) occupies 5120 shorts; frag (j,hl) at (j*2+hl)*512 + lane*8
__global__ __launch_bounds__(256) void k0_prep(const float* __restrict__ cl,
                                               unsigned short* __restrict__ Bf)
{
  int tid = blockIdx.x*256 + threadIdx.x;     // 40*256 = 10240
  int l  = tid & 63;
  int hl = (tid >> 6) & 1;
  int j  = (tid >> 7) % 5;
  int c  = tid / 640;
  int kk  = c*32 + (l>>4)*8;
  int col = j*16 + (l&15);
  unsigned short o[8];
#pragma unroll
  for (int jj=0;jj<8;jj++){
    float v = cl[(size_t)(kk+jj)*KG_ + col];
    unsigned short h = bf_rn(v);
    if (hl == 0) o[jj] = h;
    else         o[jj] = bf_rn(v - bf_up(h));
  }
  size_t base = (size_t)c*5120 + (size_t)(j*2+hl)*512 + l*8;
#pragma unroll
  for (int jj=0;jj<8;jj++) Bf[base + jj] = o[jj];
}

// ---------------- K1: a = x @ clusters + col sums + xth (x^T hi-bf16) ------
// grid 1024 (64 rows), block 256 = 4 waves; wave: 16 rows x 80 cols.
// No LDS in main loop. x prefetch depth 2, B-frags depth 1.
__global__ __launch_bounds__(256,3) void k1_proj(
    const float* __restrict__ x, const unsigned short* __restrict__ Bf,
    float* __restrict__ a, float* __restrict__ S1, float* __restrict__ S2,
    unsigned short* __restrict__ xth)
{
  __shared__ float ls1[KG_], ls2[KG_];
  const int t = threadIdx.x;
  const int w = t >> 6, lane = t & 63;
  const int m = lane & 15, q = lane >> 4;
  const int row = blockIdx.x*64 + w*16 + m;   // global row (b*2048+n)
  const int gb = row >> 11, nn = row & (N_-1);
  if (t < KG_){ ls1[t]=0.f; ls2[t]=0.f; }
  __syncthreads();

  const float* xr = x + (size_t)row*D_ + q*8;

  f32x4 acc[5];
#pragma unroll
  for (int j=0;j<5;j++) acc[j] = (f32x4){0.f,0.f,0.f,0.f};

  // x pipeline: depth 2
  float4 va0 = *(const float4*)(xr);
  float4 vb0 = *(const float4*)(xr + 4);
  float4 va1 = *(const float4*)(xr + 32);
  float4 vb1 = *(const float4*)(xr + 36);
  // B pipeline: depth 1
  short8 bf[10];
  {
    const unsigned short* bp = Bf + lane*8;
#pragma unroll
    for (int f=0; f<10; f++) bf[f] = *(const short8*)(bp + f*512);
  }

  for (int c=0;c<16;c++){
    float4 va2, vb2;
    if (c < 14){
      va2 = *(const float4*)(xr + (c+2)*32);
      vb2 = *(const float4*)(xr + (c+2)*32 + 4);
    }
    short8 nbf[10];
    if (c < 15){
      const unsigned short* np = Bf + (size_t)(c+1)*5120 + lane*8;
#pragma unroll
      for (int f=0; f<10; f++) nbf[f] = *(const short8*)(np + f*512);
    }
    float v[8] = {va0.x,va0.y,va0.z,va0.w,vb0.x,vb0.y,vb0.z,vb0.w};
    short8 ah, al;
    cvt8(v, ah, al);
    // fused transpose store: xth[gb][d][nn], d = c*32 + q*8 + j
    {
      size_t xo = ((size_t)gb*D_ + c*32 + q*8)*N_ + nn;
#pragma unroll
      for (int j=0;j<8;j++) xth[xo + (size_t)j*N_] = (unsigned short)ah[j];
    }
#pragma unroll
    for (int j=0;j<5;j++){
      acc[j] = __builtin_amdgcn_mfma_f32_16x16x32_bf16(ah, bf[2*j],   acc[j], 0,0,0);
      acc[j] = __builtin_amdgcn_mfma_f32_16x16x32_bf16(al, bf[2*j],   acc[j], 0,0,0);
      acc[j] = __builtin_amdgcn_mfma_f32_16x16x32_bf16(ah, bf[2*j+1], acc[j], 0,0,0);
    }
    va0 = va1; vb0 = vb1; va1 = va2; vb1 = vb2;
    if (c < 15){
#pragma unroll
      for (int f=0; f<10; f++) bf[f] = nbf[f];
    }
  }

  // epilogue: store a + fused column sums
  const int rowbase = blockIdx.x*64 + w*16;
  float s1v[5], s2v[5];
#pragma unroll
  for (int j=0;j<5;j++){
    f32x4 vv = acc[j];
    size_t base = (size_t)(rowbase + q*4)*KG_ + j*16 + m;
    a[base]        = vv[0];
    a[base+KG_]    = vv[1];
    a[base+2*KG_]  = vv[2];
    a[base+3*KG_]  = vv[3];
    s1v[j] = vv[0]+vv[1]+vv[2]+vv[3];
    s2v[j] = vv[0]*vv[0]+vv[1]*vv[1]+vv[2]*vv[2]+vv[3]*vv[3];
  }
#pragma unroll
  for (int j=0;j<5;j++){
    float s1 = s1v[j], s2 = s2v[j];
    s1 += __shfl_xor(s1,16); s1 += __shfl_xor(s1,32);
    s2 += __shfl_xor(s2,16); s2 += __shfl_xor(s2,32);
    if (q == 0){
      atomicAdd(&ls1[j*16+m], s1);
      atomicAdd(&ls2[j*16+m], s2);
    }
  }
  __syncthreads();
  if (t < KG_){ atomicAdd(&S1[t], ls1[t]); atomicAdd(&S2[t], ls2[t]); }
}

// ---------------- K2: BN finalize -> scale/shift ----------------
__global__ void k2_bn(const float* __restrict__ S1, const float* __restrict__ S2,
                      const float* __restrict__ gamma, const float* __restrict__ beta,
                      float* __restrict__ scale, float* __restrict__ shift)
{
  int t = threadIdx.x;
  if (t < KG_){
    const float invM = 1.0f / (float)M_;
    float mean = S1[t] * invM;
    float var  = S2[t] * invM - mean*mean;
    float sc = gamma[t] * rsqrtf(var + 1e-5f);
    scale[t] = sc;
    shift[t] = beta[t] - mean*sc;
  }
}

// ---------------- K3: BN affine + softmax -> p_t (bf16 hi/lo) + a_sum ------
__global__ __launch_bounds__(256) void k3_softmax(
    const float* __restrict__ a, const float* __restrict__ scale,
    const float* __restrict__ shift, float* __restrict__ asum,
    unsigned short* __restrict__ pth, unsigned short* __restrict__ ptl)
{
  __shared__ float as[64*84];
  __shared__ float sc[KG_], sh[KG_];
  __shared__ float lsum[KC_];
  const int t = threadIdx.x;
  const int row0 = blockIdx.x * 64;
  if (t < KG_){ sc[t]=scale[t]; sh[t]=shift[t]; }
  if (t < KC_) lsum[t]=0.f;
  __syncthreads();
#pragma unroll
  for (int l=0;l<20;l++){
    int idx = t + 256*l;
    int r = idx/80, col = idx - r*80;
    float v = a[(size_t)(row0+r)*KG_ + col];
    as[r*84+col] = v*sc[col] + sh[col];
  }
  __syncthreads();
  const int rt = t >> 2;
  const int g  = t & 3;
  float mx = -1e30f;
#pragma unroll
  for (int c=0;c<20;c++) mx = fmaxf(mx, as[rt*84 + g + 4*c]);
  mx = fmaxf(mx, __shfl_xor(mx,1));
  mx = fmaxf(mx, __shfl_xor(mx,2));
  float e[20]; float s = 0.f;
#pragma unroll
  for (int c=0;c<20;c++){ float v = __expf(as[rt*84 + g + 4*c] - mx); e[c]=v; s+=v; }
  s += __shfl_xor(s,1);
  s += __shfl_xor(s,2);
  const float inv = 1.f/s;
#pragma unroll
  for (int c=0;c<16;c++){
    int col = g + 4*c;
    float pv = e[c]*inv;
    as[rt*84 + col] = pv;              // overwrite score with prob (cols<64)
    float su = pv;
    su += __shfl_xor(su,4);  su += __shfl_xor(su,8);
    su += __shfl_xor(su,16); su += __shfl_xor(su,32);
    if ((t&63) < 4) atomicAdd(&lsum[col], su);
  }
  __syncthreads();
  // transpose: p_t[b][k][n] bf16 hi/lo, coalesced along n
  {
    const int k = t >> 2, nseg = (t & 3) * 16;
    const int b = row0 >> 11, n0 = row0 & (N_-1);
    unsigned short vh[16], vl[16];
#pragma unroll
    for (int i=0;i<16;i++){
      float v = as[(nseg+i)*84 + k];
      unsigned short h = bf_rn(v);
      vh[i] = h;
      vl[i] = bf_rn(v - bf_up(h));
    }
    size_t base = ((size_t)b*KC_ + k)*N_ + n0 + nseg;
    *(short8*)&pth[base]     = *(short8*)&vh[0];
    *(short8*)&pth[base + 8] = *(short8*)&vh[8];
    *(short8*)&ptl[base]     = *(short8*)&vl[0];
    *(short8*)&ptl[base + 8] = *(short8*)&vl[8];
  }
  if (t < KC_) atomicAdd(&asum[(blockIdx.x>>5)*KC_ + t], lsum[t]);
}

// ---------------- K4: vlad^T = p^T @ x — pure direct-frag MFMA -------------
// grid 1024 = dt(8 hi-bits) x b(32) x ns(4). block 256 = 4 waves.
// wave w: 16 kclusters (m-tile), 64 d (4 n-tiles). K = 512 n per split.
__global__ __launch_bounds__(256,4) void k4_vlad(
    const unsigned short* __restrict__ xth, const unsigned short* __restrict__ pth,
    const unsigned short* __restrict__ ptl, float* __restrict__ vp)
{
  const int t = threadIdx.x;
  const int w = t >> 6, lane = t & 63;
  const int m = lane & 15, q = lane >> 4;
  const int blk = blockIdx.x;
  const int dt = blk >> 7;          // high bits: same-(b,ns) dtiles share XCD
  const int b  = (blk >> 2) & 31;
  const int ns = blk & 3;

  const unsigned short* ap  = pth + ((size_t)b*KC_ + w*16 + m)*N_ + ns*512 + q*8;
  const unsigned short* lp  = ptl + ((size_t)b*KC_ + w*16 + m)*N_ + ns*512 + q*8;
  const unsigned short* bpx = xth + ((size_t)b*D_ + dt*64 + m)*N_ + ns*512 + q*8;

  f32x4 acc[4];
#pragma unroll
  for (int j=0;j<4;j++) acc[j] = (f32x4){0.f,0.f,0.f,0.f};

  short8 pa = *(const short8*)ap;
  short8 pl = *(const short8*)lp;
  short8 xb[4];
#pragma unroll
  for (int j=0;j<4;j++) xb[j] = *(const short8*)(bpx + (size_t)(j*16)*N_);

  for (int ch=0; ch<16; ch++){
    short8 npa, npl, nxb[4];
    if (ch < 15){
      const int no = (ch+1)*32;
      npa = *(const short8*)(ap + no);
      npl = *(const short8*)(lp + no);
#pragma unroll
      for (int j=0;j<4;j++) nxb[j] = *(const short8*)(bpx + (size_t)(j*16)*N_ + no);
    }
#pragma unroll
    for (int j=0;j<4;j++){
      acc[j] = __builtin_amdgcn_mfma_f32_16x16x32_bf16(pa, xb[j], acc[j], 0,0,0);
      acc[j] = __builtin_amdgcn_mfma_f32_16x16x32_bf16(pl, xb[j], acc[j], 0,0,0);
    }
    if (ch < 15){
      pa = npa; pl = npl;
#pragma unroll
      for (int j=0;j<4;j++) xb[j] = nxb[j];
    }
  }
  // C[m=kcluster (q*4+i within w*16)][n=d (dt*64 + j*16 + m)] -> vp[ns][b][d][k]
#pragma unroll
  for (int j=0;j<4;j++){
#pragma unroll
    for (int i=0;i<4;i++){
      int k = w*16 + q*4 + i;
      int d = dt*64 + j*16 + m;
      vp[(((size_t)ns*B_ + b)*D_ + d)*KC_ + k] = acc[j][i];
    }
  }
}

// ---------------- K5: combine 4 splits, subtract, intra+global L2 norm -----
__global__ __launch_bounds__(1024) void k5_norm(
    const float* __restrict__ vp, const float* __restrict__ c2,
    const float* __restrict__ asum, float* __restrict__ out)
{
  __shared__ float part[16][64];
  __shared__ float invd[64];
  __shared__ float gi_s;
  const int b = blockIdx.x;
  const int t = threadIdx.x;
  const int k = t & 63, dg = t >> 6;
  const float av = asum[b*KC_ + k];
  const size_t stride = (size_t)B_*D_*KC_;
  float v[32];
  float ss = 0.f;
#pragma unroll
  for (int s=0;s<32;s++){
    int d = dg + 16*s;
    size_t idx = ((size_t)b*D_ + d)*KC_ + k;
    float vv = 0.f;
#pragma unroll
    for (int nsp=0;nsp<4;nsp++) vv += vp[idx + (size_t)nsp*stride];
    vv -= c2[d*KC_ + k]*av;
    v[s] = vv;
    ss += vv*vv;
  }
  part[dg][k] = ss;
  __syncthreads();
  if (t < 64){
    float n2 = 0.f;
#pragma unroll
    for (int i=0;i<16;i++) n2 += part[i][t];
    float nn = sqrtf(n2);
    float denom = fmaxf(nn, 1e-12f);
    invd[t] = 1.f/denom;
    float ratio = nn/denom;
    float r2 = ratio*ratio;
#pragma unroll
    for (int mm=1;mm<64;mm<<=1) r2 += __shfl_xor(r2, mm);
    if (t==0){
      float g = sqrtf(r2);
      gi_s = 1.f/fmaxf(g, 1e-12f);
    }
  }
  __syncthreads();
  const float gi = gi_s;
  const float ik = invd[k];
#pragma unroll
  for (int s=0;s<32;s++){
    int d = dg + 16*s;
    out[(size_t)b*(D_*KC_) + (size_t)d*KC_ + k] = v[s]*ik*gi;
  }
}

extern "C" void kernel_launch(void* const* d_in, const int* in_sizes, int n_in,
                              void* d_out, int out_size, void* d_ws, size_t ws_size,
                              hipStream_t stream)
{
  const float* x     = (const float*)d_in[0];
  const float* cl    = (const float*)d_in[1];
  const float* c2    = (const float*)d_in[2];
  const float* gamma = (const float*)d_in[3];
  const float* beta  = (const float*)d_in[4];
  float* out = (float*)d_out;
  float* ws  = (float*)d_ws;

  // ws (floats):
  //  S1 80 | S2 80 | scale 80 | shift 80 | asum 2048   -> 2368, pad -> 4096
  //  Bf   (ushort 81920)  @4096    .. 45056
  //  a    (fp32 M*80)     @45056   .. 5287936   (vp ALIASES a after k3)
  //  pth  (ushort M*64)   @5287936 .. 7385088
  //  ptl  (ushort M*64)   @7385088 .. 9482240
  //  xth  (ushort M*512)  @9482240 .. 26259456  => total ~105 MB
  float* S1    = ws;
  float* S2    = ws + 80;
  float* scale = ws + 160;
  float* shift = ws + 240;
  float* asum  = ws + 320;
  unsigned short* Bf  = (unsigned short*)(ws + 4096);
  float* a     = ws + 45056;
  unsigned short* pth = (unsigned short*)(ws + 5287936);
  unsigned short* ptl = (unsigned short*)(ws + 7385088);
  unsigned short* xth = (unsigned short*)(ws + 9482240);
  float* vp    = a;   // alias: a dead after k3

  hipMemsetAsync(ws, 0, 2368*sizeof(float), stream);
  k0_prep   <<<40,   256, 0, stream>>>(cl, Bf);
  k1_proj   <<<1024, 256, 0, stream>>>(x, Bf, a, S1, S2, xth);
  k2_bn     <<<1,    128, 0, stream>>>(S1, S2, gamma, beta, scale, shift);
  k3_softmax<<<1024, 256, 0, stream>>>(a, scale, shift, asum, pth, ptl);
  k4_vlad   <<<1024, 256, 0, stream>>>(xth, pth, ptl, vp);
  k5_norm   <<<32,  1024, 0, stream>>>(vp, c2, asum, out);
}

// Round 6
// 279.413 us; speedup vs baseline: 1.1674x; 1.1674x over previous
//
#include <hip/hip_runtime.h>
#include <hip/hip_bf16.h>

#define B_ 32
#define N_ 2048
#define D_ 512
#define KC_ 64
#define KG_ 80
#define M_ (B_*N_)   // 65536

typedef __attribute__((ext_vector_type(8))) short short8;
typedef __attribute__((ext_vector_type(4))) float f32x4;

__device__ __forceinline__ unsigned short bf_rn(float f){
  unsigned int u = __float_as_uint(f);
  unsigned int r = u + 0x7FFFu + ((u >> 16) & 1u);
  return (unsigned short)(r >> 16);
}
__device__ __forceinline__ float bf_up(unsigned short h){
  return __uint_as_float(((unsigned int)h) << 16);
}

// fast hi/lo split via v_cvt_pk_bf16_f32
__device__ __forceinline__ void cvt8f(const float* v, short8& hi, short8& lo){
  unsigned short hs[8]; float rem[8];
#pragma unroll
  for (int i=0;i<8;i+=2){
    __hip_bfloat162 h2 = __float22bfloat162_rn(make_float2(v[i], v[i+1]));
    unsigned short a = __builtin_bit_cast(unsigned short, h2.x);
    unsigned short b = __builtin_bit_cast(unsigned short, h2.y);
    hs[i] = a; hs[i+1] = b;
    rem[i]   = v[i]   - bf_up(a);
    rem[i+1] = v[i+1] - bf_up(b);
  }
#pragma unroll
  for (int i=0;i<8;i+=2){
    __hip_bfloat162 l2 = __float22bfloat162_rn(make_float2(rem[i], rem[i+1]));
    hi[i]   = (short)hs[i];
    hi[i+1] = (short)hs[i+1];
    lo[i]   = (short)__builtin_bit_cast(unsigned short, l2.x);
    lo[i+1] = (short)__builtin_bit_cast(unsigned short, l2.y);
  }
}
// hi-only convert
__device__ __forceinline__ short8 cvt8h(const float* v){
  short8 hi;
#pragma unroll
  for (int i=0;i<8;i+=2){
    __hip_bfloat162 h2 = __float22bfloat162_rn(make_float2(v[i], v[i+1]));
    hi[i]   = (short)__builtin_bit_cast(unsigned short, h2.x);
    hi[i+1] = (short)__builtin_bit_cast(unsigned short, h2.y);
  }
  return hi;
}

// ---------------- K0: clusters -> fragment-ordered bf16 hi/lo --------------
// chunk c (32 k) occupies 5120 shorts; frag (j,hl) at (j*2+hl)*512 + lane*8
__global__ __launch_bounds__(256) void k0_prep(const float* __restrict__ cl,
                                               unsigned short* __restrict__ Bf)
{
  int tid = blockIdx.x*256 + threadIdx.x;     // 40*256 = 10240
  int l  = tid & 63;
  int hl = (tid >> 6) & 1;
  int j  = (tid >> 7) % 5;
  int c  = tid / 640;
  int kk  = c*32 + (l>>4)*8;
  int col = j*16 + (l&15);
  unsigned short o[8];
#pragma unroll
  for (int jj=0;jj<8;jj++){
    float v = cl[(size_t)(kk+jj)*KG_ + col];
    unsigned short h = bf_rn(v);
    if (hl == 0) o[jj] = h;
    else         o[jj] = bf_rn(v - bf_up(h));
  }
  size_t base = (size_t)c*5120 + (size_t)(j*2+hl)*512 + l*8;
#pragma unroll
  for (int jj=0;jj<8;jj++) Bf[base + jj] = o[jj];
}

// ---------------- K1: a = x @ clusters (MFMA, split-bf16) + col sums -------
// grid 512 (128 rows), block 256 = 4 waves; wave: 32 rows (2 tiles) x 80.
// B frags resident per chunk (VGPR budget via launch_bounds(256,3)).
__global__ __launch_bounds__(256,3) void k1_proj(
    const float* __restrict__ x, const unsigned short* __restrict__ Bf,
    float* __restrict__ a, float* __restrict__ S1, float* __restrict__ S2)
{
  __shared__ float ls1[KG_], ls2[KG_];
  const int t = threadIdx.x;
  const int w = t >> 6, lane = t & 63;
  const int m = lane & 15, q = lane >> 4;
  const int rowW = blockIdx.x*128 + w*32;
  if (t < KG_){ ls1[t]=0.f; ls2[t]=0.f; }
  __syncthreads();

  const float* xr0 = x + (size_t)(rowW + m)*D_ + q*8;
  const float* xr1 = xr0 + (size_t)16*D_;

  f32x4 acc[2][5];
#pragma unroll
  for (int rt=0;rt<2;rt++)
#pragma unroll
    for (int j=0;j<5;j++) acc[rt][j] = (f32x4){0.f,0.f,0.f,0.f};

  // x pipeline depth 1 (branchless wrap on prefetch index)
  float v0[8], v1[8];
  *(float4*)&v0[0] = *(const float4*)(xr0);
  *(float4*)&v0[4] = *(const float4*)(xr0 + 4);
  *(float4*)&v1[0] = *(const float4*)(xr1);
  *(float4*)&v1[4] = *(const float4*)(xr1 + 4);

  for (int c=0;c<16;c++){
    // B frags for this chunk: 10 x short8, all resident
    const unsigned short* bp = Bf + (size_t)c*5120 + lane*8;
    short8 bh0 = *(const short8*)(bp);
    short8 bl0 = *(const short8*)(bp + 512);
    short8 bh1 = *(const short8*)(bp + 1024);
    short8 bl1 = *(const short8*)(bp + 1536);
    short8 bh2 = *(const short8*)(bp + 2048);
    short8 bl2 = *(const short8*)(bp + 2560);
    short8 bh3 = *(const short8*)(bp + 3072);
    short8 bl3 = *(const short8*)(bp + 3584);
    short8 bh4 = *(const short8*)(bp + 4096);
    short8 bl4 = *(const short8*)(bp + 4608);
    // prefetch next x (wraps to chunk 0 on last iter; harmless L2 hit)
    const int nc = (c+1) & 15;
    float nv0[8], nv1[8];
    *(float4*)&nv0[0] = *(const float4*)(xr0 + nc*32);
    *(float4*)&nv0[4] = *(const float4*)(xr0 + nc*32 + 4);
    *(float4*)&nv1[0] = *(const float4*)(xr1 + nc*32);
    *(float4*)&nv1[4] = *(const float4*)(xr1 + nc*32 + 4);

    short8 ah0, al0, ah1, al1;
    cvt8f(v0, ah0, al0);
    cvt8f(v1, ah1, al1);

    acc[0][0] = __builtin_amdgcn_mfma_f32_16x16x32_bf16(ah0, bh0, acc[0][0], 0,0,0);
    acc[0][0] = __builtin_amdgcn_mfma_f32_16x16x32_bf16(al0, bh0, acc[0][0], 0,0,0);
    acc[0][0] = __builtin_amdgcn_mfma_f32_16x16x32_bf16(ah0, bl0, acc[0][0], 0,0,0);
    acc[1][0] = __builtin_amdgcn_mfma_f32_16x16x32_bf16(ah1, bh0, acc[1][0], 0,0,0);
    acc[1][0] = __builtin_amdgcn_mfma_f32_16x16x32_bf16(al1, bh0, acc[1][0], 0,0,0);
    acc[1][0] = __builtin_amdgcn_mfma_f32_16x16x32_bf16(ah1, bl0, acc[1][0], 0,0,0);

    acc[0][1] = __builtin_amdgcn_mfma_f32_16x16x32_bf16(ah0, bh1, acc[0][1], 0,0,0);
    acc[0][1] = __builtin_amdgcn_mfma_f32_16x16x32_bf16(al0, bh1, acc[0][1], 0,0,0);
    acc[0][1] = __builtin_amdgcn_mfma_f32_16x16x32_bf16(ah0, bl1, acc[0][1], 0,0,0);
    acc[1][1] = __builtin_amdgcn_mfma_f32_16x16x32_bf16(ah1, bh1, acc[1][1], 0,0,0);
    acc[1][1] = __builtin_amdgcn_mfma_f32_16x16x32_bf16(al1, bh1, acc[1][1], 0,0,0);
    acc[1][1] = __builtin_amdgcn_mfma_f32_16x16x32_bf16(ah1, bl1, acc[1][1], 0,0,0);

    acc[0][2] = __builtin_amdgcn_mfma_f32_16x16x32_bf16(ah0, bh2, acc[0][2], 0,0,0);
    acc[0][2] = __builtin_amdgcn_mfma_f32_16x16x32_bf16(al0, bh2, acc[0][2], 0,0,0);
    acc[0][2] = __builtin_amdgcn_mfma_f32_16x16x32_bf16(ah0, bl2, acc[0][2], 0,0,0);
    acc[1][2] = __builtin_amdgcn_mfma_f32_16x16x32_bf16(ah1, bh2, acc[1][2], 0,0,0);
    acc[1][2] = __builtin_amdgcn_mfma_f32_16x16x32_bf16(al1, bh2, acc[1][2], 0,0,0);
    acc[1][2] = __builtin_amdgcn_mfma_f32_16x16x32_bf16(ah1, bl2, acc[1][2], 0,0,0);

    acc[0][3] = __builtin_amdgcn_mfma_f32_16x16x32_bf16(ah0, bh3, acc[0][3], 0,0,0);
    acc[0][3] = __builtin_amdgcn_mfma_f32_16x16x32_bf16(al0, bh3, acc[0][3], 0,0,0);
    acc[0][3] = __builtin_amdgcn_mfma_f32_16x16x32_bf16(ah0, bl3, acc[0][3], 0,0,0);
    acc[1][3] = __builtin_amdgcn_mfma_f32_16x16x32_bf16(ah1, bh3, acc[1][3], 0,0,0);
    acc[1][3] = __builtin_amdgcn_mfma_f32_16x16x32_bf16(al1, bh3, acc[1][3], 0,0,0);
    acc[1][3] = __builtin_amdgcn_mfma_f32_16x16x32_bf16(ah1, bl3, acc[1][3], 0,0,0);

    acc[0][4] = __builtin_amdgcn_mfma_f32_16x16x32_bf16(ah0, bh4, acc[0][4], 0,0,0);
    acc[0][4] = __builtin_amdgcn_mfma_f32_16x16x32_bf16(al0, bh4, acc[0][4], 0,0,0);
    acc[0][4] = __builtin_amdgcn_mfma_f32_16x16x32_bf16(ah0, bl4, acc[0][4], 0,0,0);
    acc[1][4] = __builtin_amdgcn_mfma_f32_16x16x32_bf16(ah1, bh4, acc[1][4], 0,0,0);
    acc[1][4] = __builtin_amdgcn_mfma_f32_16x16x32_bf16(al1, bh4, acc[1][4], 0,0,0);
    acc[1][4] = __builtin_amdgcn_mfma_f32_16x16x32_bf16(ah1, bl4, acc[1][4], 0,0,0);

#pragma unroll
    for (int i=0;i<8;i++){ v0[i]=nv0[i]; v1[i]=nv1[i]; }
  }

  // epilogue: store a + fused column sums
  float s1v[5] = {0,0,0,0,0}, s2v[5] = {0,0,0,0,0};
#pragma unroll
  for (int rt=0;rt<2;rt++){
#pragma unroll
    for (int j=0;j<5;j++){
      f32x4 vv = acc[rt][j];
      size_t base = (size_t)(rowW + rt*16 + q*4)*KG_ + j*16 + m;
      a[base]        = vv[0];
      a[base+KG_]    = vv[1];
      a[base+2*KG_]  = vv[2];
      a[base+3*KG_]  = vv[3];
      s1v[j] += vv[0]+vv[1]+vv[2]+vv[3];
      s2v[j] += vv[0]*vv[0]+vv[1]*vv[1]+vv[2]*vv[2]+vv[3]*vv[3];
    }
  }
#pragma unroll
  for (int j=0;j<5;j++){
    float s1 = s1v[j], s2 = s2v[j];
    s1 += __shfl_xor(s1,16); s1 += __shfl_xor(s1,32);
    s2 += __shfl_xor(s2,16); s2 += __shfl_xor(s2,32);
    if (q == 0){
      atomicAdd(&ls1[j*16+m], s1);
      atomicAdd(&ls2[j*16+m], s2);
    }
  }
  __syncthreads();
  if (t < KG_){ atomicAdd(&S1[t], ls1[t]); atomicAdd(&S2[t], ls2[t]); }
}

// ---------------- K2: BN finalize -> scale/shift ----------------
__global__ void k2_bn(const float* __restrict__ S1, const float* __restrict__ S2,
                      const float* __restrict__ gamma, const float* __restrict__ beta,
                      float* __restrict__ scale, float* __restrict__ shift)
{
  int t = threadIdx.x;
  if (t < KG_){
    const float invM = 1.0f / (float)M_;
    float mean = S1[t] * invM;
    float var  = S2[t] * invM - mean*mean;
    float sc = gamma[t] * rsqrtf(var + 1e-5f);
    scale[t] = sc;
    shift[t] = beta[t] - mean*sc;
  }
}

// ---------------- K3: BN affine + softmax -> p_t (bf16 hi/lo) + a_sum ------
__global__ __launch_bounds__(256) void k3_softmax(
    const float* __restrict__ a, const float* __restrict__ scale,
    const float* __restrict__ shift, float* __restrict__ asum,
    unsigned short* __restrict__ pth, unsigned short* __restrict__ ptl)
{
  __shared__ float as[64*84];
  __shared__ float sc[KG_], sh[KG_];
  __shared__ float lsum[KC_];
  const int t = threadIdx.x;
  const int row0 = blockIdx.x * 64;
  if (t < KG_){ sc[t]=scale[t]; sh[t]=shift[t]; }
  if (t < KC_) lsum[t]=0.f;
  __syncthreads();
#pragma unroll
  for (int l=0;l<20;l++){
    int idx = t + 256*l;
    int r = idx/80, col = idx - r*80;
    float v = a[(size_t)(row0+r)*KG_ + col];
    as[r*84+col] = v*sc[col] + sh[col];
  }
  __syncthreads();
  const int rt = t >> 2;
  const int g  = t & 3;
  float mx = -1e30f;
#pragma unroll
  for (int c=0;c<20;c++) mx = fmaxf(mx, as[rt*84 + g + 4*c]);
  mx = fmaxf(mx, __shfl_xor(mx,1));
  mx = fmaxf(mx, __shfl_xor(mx,2));
  float e[20]; float s = 0.f;
#pragma unroll
  for (int c=0;c<20;c++){ float v = __expf(as[rt*84 + g + 4*c] - mx); e[c]=v; s+=v; }
  s += __shfl_xor(s,1);
  s += __shfl_xor(s,2);
  const float inv = 1.f/s;
#pragma unroll
  for (int c=0;c<16;c++){
    int col = g + 4*c;
    float pv = e[c]*inv;
    as[rt*84 + col] = pv;              // overwrite score with prob (cols<64)
    float su = pv;
    su += __shfl_xor(su,4);  su += __shfl_xor(su,8);
    su += __shfl_xor(su,16); su += __shfl_xor(su,32);
    if ((t&63) < 4) atomicAdd(&lsum[col], su);
  }
  __syncthreads();
  // transpose: p_t[b][k][n] bf16 hi/lo, coalesced along n
  {
    const int k = t >> 2, nseg = (t & 3) * 16;
    const int b = row0 >> 11, n0 = row0 & (N_-1);
    unsigned short vh[16], vl[16];
#pragma unroll
    for (int i=0;i<16;i++){
      float v = as[(nseg+i)*84 + k];
      unsigned short h = bf_rn(v);
      vh[i] = h;
      vl[i] = bf_rn(v - bf_up(h));
    }
    size_t base = ((size_t)b*KC_ + k)*N_ + n0 + nseg;
    *(short8*)&pth[base]     = *(short8*)&vh[0];
    *(short8*)&pth[base + 8] = *(short8*)&vh[8];
    *(short8*)&ptl[base]     = *(short8*)&vl[0];
    *(short8*)&ptl[base + 8] = *(short8*)&vl[8];
  }
  if (t < KC_) atomicAdd(&asum[(blockIdx.x>>5)*KC_ + t], lsum[t]);
}

// ---------------- K4: vlad^T = p^T @ x; p direct frags, x via small LDS ----
// grid 512 = b(32) x dt(8) x ns(2). block 256 = 4 waves (wave = ktile of 16).
// Block: 64 k x 64 d, K = 1024 n in chunks of 32.
__global__ __launch_bounds__(256,4) void k4_vlad(
    const float* __restrict__ x, const unsigned short* __restrict__ pth,
    const unsigned short* __restrict__ ptl, float* __restrict__ vp)
{
  __shared__ unsigned short xs[64*36];
  const int t = threadIdx.x;
  const int blk = blockIdx.x;
  const int ns = blk & 1;
  const int dt = (blk >> 1) & 7;
  const int b  = blk >> 4;
  const int w = t >> 6, lane = t & 63;
  const int m = lane & 15, q = lane >> 4;
  const int d0 = dt*64;
  const int nbase = ns*1024;
  const int dloc = t & 63, ng = t >> 6;

  const float* xbase = x + ((size_t)b*N_ + nbase)*D_ + d0 + dloc;
  const unsigned short* ap = pth + ((size_t)b*KC_ + w*16 + m)*N_ + nbase + q*8;
  const unsigned short* lp = ptl + ((size_t)b*KC_ + w*16 + m)*N_ + nbase + q*8;

  f32x4 acc[4];
#pragma unroll
  for (int j=0;j<4;j++) acc[j] = (f32x4){0.f,0.f,0.f,0.f};

  // preload chunk 0
  float xv[8];
#pragma unroll
  for (int jj=0;jj<8;jj++) xv[jj] = xbase[(size_t)(ng*8+jj)*D_];
  short8 pa = *(const short8*)ap;
  short8 pl = *(const short8*)lp;

  for (int ch=0; ch<32; ch++){
    __syncthreads();                       // previous readers done
    *(short8*)&xs[dloc*36 + ng*8] = cvt8h(xv);
    __syncthreads();
    // branchless prefetch of next chunk (wraps; harmless)
    const int no = ((ch+1)&31)*32;
    float nxv[8];
#pragma unroll
    for (int jj=0;jj<8;jj++) nxv[jj] = xbase[(size_t)(no + ng*8+jj)*D_];
    short8 npa = *(const short8*)(ap + no);
    short8 npl = *(const short8*)(lp + no);
    // compute
    short8 xb[4];
#pragma unroll
    for (int j=0;j<4;j++) xb[j] = *(const short8*)&xs[(j*16+m)*36 + q*8];
#pragma unroll
    for (int j=0;j<4;j++){
      acc[j] = __builtin_amdgcn_mfma_f32_16x16x32_bf16(pa, xb[j], acc[j], 0,0,0);
      acc[j] = __builtin_amdgcn_mfma_f32_16x16x32_bf16(pl, xb[j], acc[j], 0,0,0);
    }
#pragma unroll
    for (int jj=0;jj<8;jj++) xv[jj] = nxv[jj];
    pa = npa; pl = npl;
  }
  // C[m-dim = k = w*16+q*4+i][n-dim = d = d0+j*16+m] -> vp[ns][b][d][k]
#pragma unroll
  for (int j=0;j<4;j++){
#pragma unroll
    for (int i=0;i<4;i++){
      int k = w*16 + q*4 + i;
      int d = d0 + j*16 + m;
      vp[(((size_t)ns*B_ + b)*D_ + d)*KC_ + k] = acc[j][i];
    }
  }
}

// ---------------- K5: combine 2 splits, subtract, intra+global L2 norm -----
__global__ __launch_bounds__(1024) void k5_norm(
    const float* __restrict__ vp, const float* __restrict__ c2,
    const float* __restrict__ asum, float* __restrict__ out)
{
  __shared__ float part[16][64];
  __shared__ float invd[64];
  __shared__ float gi_s;
  const int b = blockIdx.x;
  const int t = threadIdx.x;
  const int k = t & 63, dg = t >> 6;
  const float av = asum[b*KC_ + k];
  const size_t stride = (size_t)B_*D_*KC_;
  float v[32];
  float ss = 0.f;
#pragma unroll
  for (int s=0;s<32;s++){
    int d = dg + 16*s;
    size_t idx = ((size_t)b*D_ + d)*KC_ + k;
    float vv = vp[idx] + vp[idx + stride];
    vv -= c2[d*KC_ + k]*av;
    v[s] = vv;
    ss += vv*vv;
  }
  part[dg][k] = ss;
  __syncthreads();
  if (t < 64){
    float n2 = 0.f;
#pragma unroll
    for (int i=0;i<16;i++) n2 += part[i][t];
    float nn = sqrtf(n2);
    float denom = fmaxf(nn, 1e-12f);
    invd[t] = 1.f/denom;
    float ratio = nn/denom;
    float r2 = ratio*ratio;
#pragma unroll
    for (int mm=1;mm<64;mm<<=1) r2 += __shfl_xor(r2, mm);
    if (t==0){
      float g = sqrtf(r2);
      gi_s = 1.f/fmaxf(g, 1e-12f);
    }
  }
  __syncthreads();
  const float gi = gi_s;
  const float ik = invd[k];
#pragma unroll
  for (int s=0;s<32;s++){
    int d = dg + 16*s;
    out[(size_t)b*(D_*KC_) + (size_t)d*KC_ + k] = v[s]*ik*gi;
  }
}

extern "C" void kernel_launch(void* const* d_in, const int* in_sizes, int n_in,
                              void* d_out, int out_size, void* d_ws, size_t ws_size,
                              hipStream_t stream)
{
  const float* x     = (const float*)d_in[0];
  const float* cl    = (const float*)d_in[1];
  const float* c2    = (const float*)d_in[2];
  const float* gamma = (const float*)d_in[3];
  const float* beta  = (const float*)d_in[4];
  float* out = (float*)d_out;
  float* ws  = (float*)d_ws;

  // ws (floats):
  //  S1 80 | S2 80 | scale 80 | shift 80 | asum 2048 -> 2368, pad -> 4096
  //  Bf   (ushort 81920)  @4096    .. 45056
  //  a    (fp32 M*80)     @45056   .. 5287936   (vp [2*B*D*KC]=4.2M fl aliases a)
  //  pth  (ushort M*64)   @5287936 .. 7385088
  //  ptl  (ushort M*64)   @7385088 .. 9482240   (~37.9 MB total)
  float* S1    = ws;
  float* S2    = ws + 80;
  float* scale = ws + 160;
  float* shift = ws + 240;
  float* asum  = ws + 320;
  unsigned short* Bf  = (unsigned short*)(ws + 4096);
  float* a     = ws + 45056;
  unsigned short* pth = (unsigned short*)(ws + 5287936);
  unsigned short* ptl = (unsigned short*)(ws + 7385088);
  float* vp    = a;   // alias: a dead after k3

  hipMemsetAsync(ws, 0, 2368*sizeof(float), stream);
  k0_prep   <<<40,   256, 0, stream>>>(cl, Bf);
  k1_proj   <<<512,  256, 0, stream>>>(x, Bf, a, S1, S2);
  k2_bn     <<<1,    128, 0, stream>>>(S1, S2, gamma, beta, scale, shift);
  k3_softmax<<<1024, 256, 0, stream>>>(a, scale, shift, asum, pth, ptl);
  k4_vlad   <<<512,  256, 0, stream>>>(x, pth, ptl, vp);
  k5_norm   <<<32,  1024, 0, stream>>>(vp, c2, asum, out);
}